// Round 1
// baseline (160.650 us; speedup 1.0000x reference)
//
#include <hip/hip_runtime.h>
#include <math.h>

#define H 1536
#define W 2048
#define NPIX (H*W)
#define SS 2000
#define SIDE 20
#define THRC 0.2f
#define TPB 256
#define NB (NPIX/TPB)   // 12288

// ---------------- workspace layout (bytes) ----------------
constexpr size_t OFF_FLAGS = 0;                       // uint8[NPIX]
constexpr size_t OFF_PART  = (size_t)NPIX;            // float[NB*8]
constexpr size_t OFF_MEANS = OFF_PART + (size_t)NB*8*4;   // float[8]
constexpr size_t OFF_CNTL  = OFF_MEANS + 64;          // int[NB]
constexpr size_t OFF_CNTR  = OFF_CNTL + (size_t)NB*4; // int[NB]
constexpr size_t OFF_OFSL  = OFF_CNTR + (size_t)NB*4; // int[NB]
constexpr size_t OFF_OFSR  = OFF_OFSL + (size_t)NB*4; // int[NB]
constexpr size_t OFF_TOT   = OFF_OFSR + (size_t)NB*4; // int[4]: Nl, Nr, validCluster
constexpr size_t OFF_POSL  = OFF_TOT + 64;            // int[SS]
constexpr size_t OFF_POSR  = OFF_POSL + (size_t)SS*4; // int[SS]
constexpr size_t OFF_ROW   = OFF_POSR + (size_t)SS*4; // int[4*H]: lsum,lcnt,rsum,rcnt

// ---------------- math helpers (contract off: match numpy per-op rounding) ----
struct F3 { float x, y, z; };
struct K9 { float k[9]; };

__device__ __forceinline__ F3 camAt(const float* __restrict__ depth, const K9& Ki, int y, int x) {
#pragma clang fp contract(off)
    float d = depth[y * W + x];
    float u = (float)x, v = (float)y;
    F3 p;
    p.x = (Ki.k[0] * u + Ki.k[1] * v + Ki.k[2]) * d;
    p.y = (Ki.k[3] * u + Ki.k[4] * v + Ki.k[5]) * d;
    p.z = (Ki.k[6] * u + Ki.k[7] * v + Ki.k[8]) * d;
    return p;
}

__device__ __forceinline__ F3 f3sub(F3 a, F3 b) {
#pragma clang fp contract(off)
    F3 r; r.x = a.x - b.x; r.y = a.y - b.y; r.z = a.z - b.z; return r;
}

// cross(a,b) then v/(||v||+1e-6)
__device__ __forceinline__ F3 crossn(F3 a, F3 b) {
#pragma clang fp contract(off)
    F3 c;
    c.x = a.y * b.z - a.z * b.y;
    c.y = a.z * b.x - a.x * b.z;
    c.z = a.x * b.y - a.y * b.x;
    float n = sqrtf(c.x * c.x + c.y * c.y + c.z * c.z) + 1e-6f;
    c.x = c.x / n; c.y = c.y / n; c.z = c.z / n;
    return c;
}

// full surface normal at interior pixel (caller guarantees interior)
__device__ __forceinline__ F3 surfNormal(const float* __restrict__ depth, const K9& Ki, int y, int x) {
#pragma clang fp contract(off)
    F3 ctr  = camAt(depth, Ki, y, x);
    F3 x0   = camAt(depth, Ki, y, x - 1);
    F3 x1   = camAt(depth, Ki, y, x + 1);
    F3 y0   = camAt(depth, Ki, y - 1, x);
    F3 y1   = camAt(depth, Ki, y + 1, x);
    F3 x0y0 = camAt(depth, Ki, y - 1, x - 1);
    F3 x0y1 = camAt(depth, Ki, y + 1, x - 1);
    F3 x1y0 = camAt(depth, Ki, y - 1, x + 1);
    F3 x1y1 = camAt(depth, Ki, y + 1, x + 1);
    F3 n0 = crossn(f3sub(x0, ctr),   f3sub(y0, ctr));
    F3 n1 = crossn(f3sub(x1, ctr),   f3sub(y1, ctr));
    F3 n2 = crossn(f3sub(x0y0, ctr), f3sub(x0y1, ctr));
    F3 n3 = crossn(f3sub(x1y0, ctr), f3sub(x1y1, ctr));
    F3 s;
    s.x = (((n0.x + n1.x) + n2.x) + n3.x) / 4.0f;
    s.y = (((n0.y + n1.y) + n2.y) + n3.y) / 4.0f;
    s.z = (((n0.z + n1.z) + n2.z) + n3.z) / 4.0f;
    float n = sqrtf(s.x * s.x + s.y * s.y + s.z * s.z) + 1e-6f;
    s.x = s.x / n; s.y = s.y / n; s.z = s.z / n;
    return s;
}

// ---------------- K1: region flags + block partial sums of normals ----------
__global__ void k_region_partial(const float* __restrict__ depth,
                                 const int* __restrict__ mask,
                                 const float* __restrict__ Kinv,
                                 unsigned char* __restrict__ flags,
                                 float* __restrict__ partials) {
    int p = blockIdx.x * TPB + threadIdx.x;
    int y = p / W, x = p % W;
    int m = mask[p];
    bool inL = false, inR = false;
    if (!m) {
        int xa = max(0, x - SIDE), xb = min(W - 1, x + SIDE);
        const int* mrow = mask + y * W;
        for (int xx = xa; xx <= xb; ++xx) {
            int mc = mrow[xx];
            int mn = (xx < W - 1) ? mrow[xx + 1] : 0;
            inL = inL || (!mc && mn);   // grad == +1 at xx
            inR = inR || (mc && !mn);   // grad == -1 at xx
        }
    }
    float nx = 0.f, ny = 0.f, nz = 0.f;
    if ((inL || inR) && x > 0 && x < W - 1 && y > 0 && y < H - 1) {
        K9 kk;
#pragma unroll
        for (int i = 0; i < 9; ++i) kk.k[i] = Kinv[i];
        F3 n = surfNormal(depth, kk, y, x);
        nx = n.x; ny = n.y; nz = n.z;
    }
    flags[p] = (unsigned char)((inL ? 1 : 0) | (inR ? 2 : 0));

    float v[8];
    v[0] = inL ? nx : 0.f; v[1] = inL ? ny : 0.f; v[2] = inL ? nz : 0.f; v[3] = inL ? 1.f : 0.f;
    v[4] = inR ? nx : 0.f; v[5] = inR ? ny : 0.f; v[6] = inR ? nz : 0.f; v[7] = inR ? 1.f : 0.f;

    __shared__ float sred[TPB][8];
#pragma unroll
    for (int k = 0; k < 8; ++k) sred[threadIdx.x][k] = v[k];
    __syncthreads();
    for (int s = TPB / 2; s > 0; s >>= 1) {
        if (threadIdx.x < s) {
#pragma unroll
            for (int k = 0; k < 8; ++k) sred[threadIdx.x][k] += sred[threadIdx.x + s][k];
        }
        __syncthreads();
    }
    if (threadIdx.x == 0) {
#pragma unroll
        for (int k = 0; k < 8; ++k) partials[(size_t)blockIdx.x * 8 + k] = sred[0][k];
    }
}

// ---------------- K2: deterministic reduce -> normalized mean normals -------
__global__ void k_mean(const float* __restrict__ partials, float* __restrict__ means) {
#pragma clang fp contract(off)
    __shared__ float sred[256][8];
    float acc[8];
#pragma unroll
    for (int k = 0; k < 8; ++k) acc[k] = 0.f;
    for (int i = threadIdx.x; i < NB; i += 256) {
#pragma unroll
        for (int k = 0; k < 8; ++k) acc[k] += partials[(size_t)i * 8 + k];
    }
#pragma unroll
    for (int k = 0; k < 8; ++k) sred[threadIdx.x][k] = acc[k];
    __syncthreads();
    for (int s = 128; s > 0; s >>= 1) {
        if (threadIdx.x < s) {
#pragma unroll
            for (int k = 0; k < 8; ++k) sred[threadIdx.x][k] += sred[threadIdx.x + s][k];
        }
        __syncthreads();
    }
    if (threadIdx.x == 0) {
        // left
        {
            float cnt = fmaxf(sred[0][3], 1.f);
            float mx = sred[0][0] / cnt, my = sred[0][1] / cnt, mz = sred[0][2] / cnt;
            float n = sqrtf(mx * mx + my * my + mz * mz);
            float nn = fmaxf(n, 1e-12f);
            mx = mx / nn; my = my / nn; mz = mz / nn;
            float n2 = sqrtf(mx * mx + my * my + mz * mz);
            means[0] = mx; means[1] = my; means[2] = mz; means[3] = n2;
        }
        // right
        {
            float cnt = fmaxf(sred[0][7], 1.f);
            float mx = sred[0][4] / cnt, my = sred[0][5] / cnt, mz = sred[0][6] / cnt;
            float n = sqrtf(mx * mx + my * my + mz * mz);
            float nn = fmaxf(n, 1e-12f);
            mx = mx / nn; my = my / nn; mz = mz / nn;
            float n2 = sqrtf(mx * mx + my * my + mz * mz);
            means[4] = mx; means[5] = my; means[6] = mz; means[7] = n2;
        }
    }
}

// ---------------- K3: inlier flags + per-block inlier counts ----------------
__global__ void k_inlier(const float* __restrict__ depth,
                         const float* __restrict__ Kinv,
                         unsigned char* __restrict__ flags,
                         const float* __restrict__ means,
                         int* __restrict__ cntsL, int* __restrict__ cntsR) {
#pragma clang fp contract(off)
    int p = blockIdx.x * TPB + threadIdx.x;
    unsigned char f = flags[p];
    bool il = false, ir = false;
    if (f & 3) {
        int y = p / W, x = p % W;
        float nx = 0.f, ny = 0.f, nz = 0.f;
        if (x > 0 && x < W - 1 && y > 0 && y < H - 1) {
            K9 kk;
#pragma unroll
            for (int i = 0; i < 9; ++i) kk.k[i] = Kinv[i];
            F3 n = surfNormal(depth, kk, y, x);
            nx = n.x; ny = n.y; nz = n.z;
        }
        float nn = sqrtf(nx * nx + ny * ny + nz * nz);
        float dn = fmaxf(nn, 1e-8f);
        if (f & 1) {
            float dot = nx * means[0] + ny * means[1] + nz * means[2];
            float c = dot / (dn * fmaxf(means[3], 1e-8f));
            il = c > THRC;
        }
        if (f & 2) {
            float dot = nx * means[4] + ny * means[5] + nz * means[6];
            float c = dot / (dn * fmaxf(means[7], 1e-8f));
            ir = c > THRC;
        }
    }
    flags[p] = (unsigned char)(f | (il ? 4 : 0) | (ir ? 8 : 0));

    unsigned long long bl = __ballot(il), br = __ballot(ir);
    __shared__ int swl[4], swr[4];
    int wave = threadIdx.x >> 6, lane = threadIdx.x & 63;
    if (lane == 0) { swl[wave] = __popcll(bl); swr[wave] = __popcll(br); }
    __syncthreads();
    if (threadIdx.x == 0) {
        cntsL[blockIdx.x] = swl[0] + swl[1] + swl[2] + swl[3];
        cntsR[blockIdx.x] = swr[0] + swr[1] + swr[2] + swr[3];
    }
}

// ---------------- K4: scan counts -> offsets, totals, pos arrays ------------
__device__ __forceinline__ int computePos(int i, int N) {
    if (N >= SS) {
        float t = ((float)i * (float)(N - 1)) / 1999.0f;  // float32, exact reference parity
        return (int)floorf(t);
    } else {
        return min(i, max(N - 1, 0));
    }
}

__global__ void k_scan(const int* __restrict__ cntsL, const int* __restrict__ cntsR,
                       int* __restrict__ ofsL, int* __restrict__ ofsR,
                       int* __restrict__ totals,
                       int* __restrict__ posL, int* __restrict__ posR) {
    __shared__ int sL[1024], sR[1024];
    __shared__ int sN[2];
    int t = threadIdx.x;
    const int CH = NB / 1024;  // 12
    int lo = t * CH, hi = lo + CH;
    int sl = 0, sr = 0;
    for (int i = lo; i < hi; ++i) { sl += cntsL[i]; sr += cntsR[i]; }
    sL[t] = sl; sR[t] = sr;
    __syncthreads();
    for (int off = 1; off < 1024; off <<= 1) {
        int vl = 0, vr = 0;
        if (t >= off) { vl = sL[t - off]; vr = sR[t - off]; }
        __syncthreads();
        sL[t] += vl; sR[t] += vr;
        __syncthreads();
    }
    // exclusive base for my chunk
    int baseL = sL[t] - sl, baseR = sR[t] - sr;
    int runL = baseL, runR = baseR;
    for (int i = lo; i < hi; ++i) {
        ofsL[i] = runL; runL += cntsL[i];
        ofsR[i] = runR; runR += cntsR[i];
    }
    if (t == 1023) {
        sN[0] = sL[1023]; sN[1] = sR[1023];
        totals[0] = sN[0]; totals[1] = sN[1];
        totals[2] = (sN[0] > 0 && sN[1] > 0) ? 1 : 0;
        totals[3] = 0;
    }
    __syncthreads();
    int Nl = sN[0], Nr = sN[1];
    for (int i = t; i < SS; i += 1024) {
        posL[i] = computePos(i, Nl);
        posR[i] = computePos(i, Nr);
    }
}

// ---------------- K5: ordered compaction rank -> sampled row sums -----------
__device__ __forceinline__ int lowerBound(const int* __restrict__ a, int n, int v) {
    int lo = 0, hi = n;
    while (lo < hi) { int mid = (lo + hi) >> 1; if (a[mid] < v) lo = mid + 1; else hi = mid; }
    return lo;
}
__device__ __forceinline__ int upperBound(const int* __restrict__ a, int n, int v) {
    int lo = 0, hi = n;
    while (lo < hi) { int mid = (lo + hi) >> 1; if (a[mid] <= v) lo = mid + 1; else hi = mid; }
    return lo;
}

__global__ void k_sample(const unsigned char* __restrict__ flags,
                         const int* __restrict__ ofsL, const int* __restrict__ ofsR,
                         const int* __restrict__ totals,
                         const int* __restrict__ posL, const int* __restrict__ posR,
                         int* __restrict__ rowAcc) {
    if (!totals[2]) return;  // invalid cluster -> output falls back to depth
    int p = blockIdx.x * TPB + threadIdx.x;
    unsigned char f = flags[p];
    bool il = (f & 4) != 0, ir = (f & 8) != 0;

    unsigned long long bl = __ballot(il), br = __ballot(ir);
    __shared__ int swl[4], swr[4];
    int wave = threadIdx.x >> 6, lane = threadIdx.x & 63;
    if (lane == 0) { swl[wave] = __popcll(bl); swr[wave] = __popcll(br); }
    __syncthreads();
    int baseL = ofsL[blockIdx.x], baseR = ofsR[blockIdx.x];
    for (int w = 0; w < wave; ++w) { baseL += swl[w]; baseR += swr[w]; }
    unsigned long long lmask = (lane == 0) ? 0ull : ((~0ull) >> (64 - lane));
    if (il) {
        int r = baseL + __popcll(bl & lmask);
        int lo = lowerBound(posL, SS, r), hi = upperBound(posL, SS, r);
        int c = hi - lo;
        if (c > 0) {
            int y = p / W, x = p % W;
            atomicAdd(&rowAcc[y], c * x);
            atomicAdd(&rowAcc[H + y], c);
        }
    }
    if (ir) {
        int r = baseR + __popcll(br & lmask);
        int lo = lowerBound(posR, SS, r), hi = upperBound(posR, SS, r);
        int c = hi - lo;
        if (c > 0) {
            int y = p / W, x = p % W;
            atomicAdd(&rowAcc[2 * H + y], c * x);
            atomicAdd(&rowAcc[3 * H + y], c);
        }
    }
}

// ---------------- K6: per-row interpolation + output ------------------------
__global__ void k_out(const float* __restrict__ depth, const int* __restrict__ mask,
                      const int* __restrict__ rowAcc, const int* __restrict__ totals,
                      float* __restrict__ out) {
#pragma clang fp contract(off)
    int y = blockIdx.x, t = threadIdx.x;
    __shared__ int sAny;
    __shared__ float sld, srd, slx, srx;
    __shared__ int svalid;
    if (t == 0) sAny = 0;
    __syncthreads();
    int m8[8]; float d8[8];
    int any = 0;
#pragma unroll
    for (int j = 0; j < 8; ++j) {
        int x = j * 256 + t;
        m8[j] = mask[y * W + x];
        d8[j] = depth[y * W + x];
        any |= m8[j];
    }
    if (any) atomicOr(&sAny, 1);
    __syncthreads();
    if (t == 0) {
        int lc = rowAcc[H + y], rc = rowAcc[3 * H + y];
        float lmean = (float)rowAcc[y] / fmaxf((float)lc, 1.0f);
        float rmean = (float)rowAcc[2 * H + y] / fmaxf((float)rc, 1.0f);
        int lx = min(max((int)rintf(lmean), 0), W - 1);
        int rx = min(max((int)rintf(rmean), 0), W - 1);
        float ld = depth[y * W + lx], rd = depth[y * W + rx];
        int valid = (lc > 0) && (rc > 0) && (totals[2] != 0) &&
                    (!isnan(ld)) && (!isnan(rd)) && (sAny != 0);
        sld = ld; srd = rd; slx = (float)lx; srx = (float)rx; svalid = valid;
    }
    __syncthreads();
#pragma unroll
    for (int j = 0; j < 8; ++j) {
        int x = j * 256 + t;
        float o = d8[j];
        if (m8[j] && svalid) {
            float r = ((float)x - slx) / ((srx - slx) + 1e-6f);
            r = fminf(fmaxf(r, 0.0f), 1.0f);
            o = (1.0f - r) * sld + r * srd;
        }
        out[y * W + x] = o;
    }
}

// ---------------- launcher ---------------------------------------------------
extern "C" void kernel_launch(void* const* d_in, const int* in_sizes, int n_in,
                              void* d_out, int out_size, void* d_ws, size_t ws_size,
                              hipStream_t stream) {
    const float* depth = (const float*)d_in[0];
    const int*   mask  = (const int*)d_in[1];
    const float* Kinv  = (const float*)d_in[2];
    float* out = (float*)d_out;
    char* ws = (char*)d_ws;

    unsigned char* flags = (unsigned char*)(ws + OFF_FLAGS);
    float* partials = (float*)(ws + OFF_PART);
    float* means    = (float*)(ws + OFF_MEANS);
    int* cntsL = (int*)(ws + OFF_CNTL);
    int* cntsR = (int*)(ws + OFF_CNTR);
    int* ofsL  = (int*)(ws + OFF_OFSL);
    int* ofsR  = (int*)(ws + OFF_OFSR);
    int* totals = (int*)(ws + OFF_TOT);
    int* posL  = (int*)(ws + OFF_POSL);
    int* posR  = (int*)(ws + OFF_POSR);
    int* rowAcc = (int*)(ws + OFF_ROW);

    hipMemsetAsync(rowAcc, 0, (size_t)4 * H * sizeof(int), stream);

    k_region_partial<<<NB, TPB, 0, stream>>>(depth, mask, Kinv, flags, partials);
    k_mean<<<1, 256, 0, stream>>>(partials, means);
    k_inlier<<<NB, TPB, 0, stream>>>(depth, Kinv, flags, means, cntsL, cntsR);
    k_scan<<<1, 1024, 0, stream>>>(cntsL, cntsR, ofsL, ofsR, totals, posL, posR);
    k_sample<<<NB, TPB, 0, stream>>>(flags, ofsL, ofsR, totals, posL, posR, rowAcc);
    k_out<<<H, 256, 0, stream>>>(depth, mask, rowAcc, totals, out);
}

// Round 3
// 94.546 us; speedup vs baseline: 1.6992x; 1.6992x over previous
//
#include <hip/hip_runtime.h>
#include <math.h>

#define H 1536
#define W 2048
#define NPIX (H*W)
#define SS 2000
#define SIDE 20
#define THRC 0.2f

typedef unsigned long long u64;

// ---------------- workspace layout (bytes) ----------------
constexpr size_t OFF_BITL  = 0;                            // u64[H*32]  384 KB
constexpr size_t OFF_BITR  = OFF_BITL + (size_t)H*32*8;    // u64[H*32]  384 KB
constexpr size_t OFF_PART  = OFF_BITR + (size_t)H*32*8;    // float[H*8]  48 KB
constexpr size_t OFF_MEANS = OFF_PART + (size_t)H*8*4;     // float[8]
constexpr size_t OFF_CNTL  = OFF_MEANS + 64;               // int[H]
constexpr size_t OFF_CNTR  = OFF_CNTL + (size_t)H*4;       // int[H]
constexpr size_t OFF_TOT   = OFF_CNTR + (size_t)H*4;       // int[4]
constexpr size_t OFF_ROW   = OFF_TOT + 64;                 // int[4*H]

// ---------------- math helpers (contract off: match numpy per-op rounding) ----
struct F3 { float x, y, z; };
struct K9 { float k[9]; };

__device__ __forceinline__ F3 camAt(const float* __restrict__ depth, const K9& Ki, int y, int x) {
#pragma clang fp contract(off)
    float d = depth[y * W + x];
    float u = (float)x, v = (float)y;
    F3 p;
    p.x = (Ki.k[0] * u + Ki.k[1] * v + Ki.k[2]) * d;
    p.y = (Ki.k[3] * u + Ki.k[4] * v + Ki.k[5]) * d;
    p.z = (Ki.k[6] * u + Ki.k[7] * v + Ki.k[8]) * d;
    return p;
}

__device__ __forceinline__ F3 f3sub(F3 a, F3 b) {
#pragma clang fp contract(off)
    F3 r; r.x = a.x - b.x; r.y = a.y - b.y; r.z = a.z - b.z; return r;
}

__device__ __forceinline__ F3 crossn(F3 a, F3 b) {
#pragma clang fp contract(off)
    F3 c;
    c.x = a.y * b.z - a.z * b.y;
    c.y = a.z * b.x - a.x * b.z;
    c.z = a.x * b.y - a.y * b.x;
    float n = sqrtf(c.x * c.x + c.y * c.y + c.z * c.z) + 1e-6f;
    c.x = c.x / n; c.y = c.y / n; c.z = c.z / n;
    return c;
}

__device__ __forceinline__ F3 surfNormal(const float* __restrict__ depth, const K9& Ki, int y, int x) {
#pragma clang fp contract(off)
    F3 ctr  = camAt(depth, Ki, y, x);
    F3 x0   = camAt(depth, Ki, y, x - 1);
    F3 x1   = camAt(depth, Ki, y, x + 1);
    F3 y0   = camAt(depth, Ki, y - 1, x);
    F3 y1   = camAt(depth, Ki, y + 1, x);
    F3 x0y0 = camAt(depth, Ki, y - 1, x - 1);
    F3 x0y1 = camAt(depth, Ki, y + 1, x - 1);
    F3 x1y0 = camAt(depth, Ki, y - 1, x + 1);
    F3 x1y1 = camAt(depth, Ki, y + 1, x + 1);
    F3 n0 = crossn(f3sub(x0, ctr),   f3sub(y0, ctr));
    F3 n1 = crossn(f3sub(x1, ctr),   f3sub(y1, ctr));
    F3 n2 = crossn(f3sub(x0y0, ctr), f3sub(x0y1, ctr));
    F3 n3 = crossn(f3sub(x1y0, ctr), f3sub(x1y1, ctr));
    F3 s;
    s.x = (((n0.x + n1.x) + n2.x) + n3.x) / 4.0f;
    s.y = (((n0.y + n1.y) + n2.y) + n3.y) / 4.0f;
    s.z = (((n0.z + n1.z) + n2.z) + n3.z) / 4.0f;
    float n = sqrtf(s.x * s.x + s.y * s.y + s.z * s.z) + 1e-6f;
    s.x = s.x / n; s.y = s.y / n; s.z = s.z / n;
    return s;
}

// ---------------- K1: per-row region bitmaps + per-row normal partials ------
__global__ void k_row_region(const float* __restrict__ depth,
                             const int* __restrict__ mask,
                             const float* __restrict__ Kinv,
                             u64* __restrict__ bitL, u64* __restrict__ bitR,
                             float* __restrict__ partials) {
    int y = blockIdx.x, t = threadIdx.x;
    __shared__ u64 wM[32];
    __shared__ u64 wE0[32], wE1[32];
    __shared__ unsigned char pbA[256];
    __shared__ unsigned char pbB[256];

    // load this thread's 8 mask pixels (x = 8t .. 8t+7)
    const int4* mrow = reinterpret_cast<const int4*>(mask + (size_t)y * W);
    int4 a = mrow[t * 2], b = mrow[t * 2 + 1];
    unsigned mbyte =
        ((unsigned)(a.x != 0))      | ((unsigned)(a.y != 0) << 1) |
        ((unsigned)(a.z != 0) << 2) | ((unsigned)(a.w != 0) << 3) |
        ((unsigned)(b.x != 0) << 4) | ((unsigned)(b.y != 0) << 5) |
        ((unsigned)(b.z != 0) << 6) | ((unsigned)(b.w != 0) << 7);
    pbA[t] = (unsigned char)mbyte;
    __syncthreads();
    if (t < 32) wM[t] = reinterpret_cast<u64*>(pbA)[t];
    __syncthreads();
    if (t < 32) {
        u64 M  = wM[t];
        u64 Mn = (M >> 1) | ((t < 31) ? (wM[t + 1] << 63) : 0ull);  // m[x+1], pad 0
        wE0[t] = ~M & Mn;   // left edges  (grad == +1)
        wE1[t] = M & ~Mn;   // right edges (grad == -1)
    }
    __syncthreads();

    // 48-bit edge window covering pixels [8t-20, 8t+27]
    int base = t * 8 - SIDE;
    int wi = base >> 6;
    int ofs = base & 63;
    u64 l0 = (wi >= 0)    ? wE0[wi]     : 0ull;
    u64 l1 = (wi + 1 < 32)? wE0[wi + 1] : 0ull;
    u64 r0 = (wi >= 0)    ? wE1[wi]     : 0ull;
    u64 r1 = (wi + 1 < 32)? wE1[wi + 1] : 0ull;
    u64 winL = ofs ? ((l0 >> ofs) | (l1 << (64 - ofs))) : l0;
    u64 winR = ofs ? ((r0 >> ofs) | (r1 << (64 - ofs))) : r0;

    const u64 M41 = (1ull << 41) - 1;
    unsigned bL = 0, bR = 0;
#pragma unroll
    for (int j = 0; j < 8; ++j) {
        unsigned notm = (((mbyte >> j) & 1u) ^ 1u);
        unsigned dl = (((winL >> j) & M41) != 0ull) ? 1u : 0u;
        unsigned dr = (((winR >> j) & M41) != 0ull) ? 1u : 0u;
        bL |= (dl & notm) << j;
        bR |= (dr & notm) << j;
    }
    unsigned bAny = bL | bR;

    // pack region bitmaps to global
    pbA[t] = (unsigned char)bL;
    pbB[t] = (unsigned char)bR;
    __syncthreads();
    if (t < 32) {
        bitL[(size_t)y * 32 + t] = reinterpret_cast<u64*>(pbA)[t];
        bitR[(size_t)y * 32 + t] = reinterpret_cast<u64*>(pbB)[t];
    }

    int anyblk = __syncthreads_or((int)bAny);
    if (!anyblk) {
        if (t == 0) {
#pragma unroll
            for (int k = 0; k < 8; ++k) partials[(size_t)y * 8 + k] = 0.f;
        }
        return;
    }

    float acc[8];
#pragma unroll
    for (int k = 0; k < 8; ++k) acc[k] = 0.f;
    if (bAny) {
        K9 kk;
#pragma unroll
        for (int i = 0; i < 9; ++i) kk.k[i] = Kinv[i];
        for (int j = 0; j < 8; ++j) {
            if (!((bAny >> j) & 1u)) continue;
            int x = t * 8 + j;
            float nx = 0.f, ny = 0.f, nz = 0.f;
            if (x > 0 && x < W - 1 && y > 0 && y < H - 1) {
                F3 n = surfNormal(depth, kk, y, x);
                nx = n.x; ny = n.y; nz = n.z;
            }
            if ((bL >> j) & 1u) { acc[0] += nx; acc[1] += ny; acc[2] += nz; acc[3] += 1.f; }
            if ((bR >> j) & 1u) { acc[4] += nx; acc[5] += ny; acc[6] += nz; acc[7] += 1.f; }
        }
    }
    // wave reduce then cross-wave (deterministic fixed tree)
    __shared__ float swred[4][8];
    int wave = t >> 6, lane = t & 63;
#pragma unroll
    for (int k = 0; k < 8; ++k) {
        float v = acc[k];
        for (int o = 32; o > 0; o >>= 1) v += __shfl_down(v, o, 64);
        if (lane == 0) swred[wave][k] = v;
    }
    __syncthreads();
    if (t == 0) {
#pragma unroll
        for (int k = 0; k < 8; ++k)
            partials[(size_t)y * 8 + k] = ((swred[0][k] + swred[1][k]) + swred[2][k]) + swred[3][k];
    }
}

// ---------------- K2: reduce per-row partials -> normalized mean normals ----
__global__ void k_mean(const float* __restrict__ partials, float* __restrict__ means) {
#pragma clang fp contract(off)
    __shared__ float sred[256][8];
    float acc[8];
#pragma unroll
    for (int k = 0; k < 8; ++k) acc[k] = 0.f;
    for (int i = threadIdx.x; i < H; i += 256) {
#pragma unroll
        for (int k = 0; k < 8; ++k) acc[k] += partials[(size_t)i * 8 + k];
    }
#pragma unroll
    for (int k = 0; k < 8; ++k) sred[threadIdx.x][k] = acc[k];
    __syncthreads();
    for (int s = 128; s > 0; s >>= 1) {
        if (threadIdx.x < s) {
#pragma unroll
            for (int k = 0; k < 8; ++k) sred[threadIdx.x][k] += sred[threadIdx.x + s][k];
        }
        __syncthreads();
    }
    if (threadIdx.x == 0) {
        {
            float cnt = fmaxf(sred[0][3], 1.f);
            float mx = sred[0][0] / cnt, my = sred[0][1] / cnt, mz = sred[0][2] / cnt;
            float n = sqrtf(mx * mx + my * my + mz * mz);
            float nn = fmaxf(n, 1e-12f);
            mx = mx / nn; my = my / nn; mz = mz / nn;
            float n2 = sqrtf(mx * mx + my * my + mz * mz);
            means[0] = mx; means[1] = my; means[2] = mz; means[3] = n2;
        }
        {
            float cnt = fmaxf(sred[0][7], 1.f);
            float mx = sred[0][4] / cnt, my = sred[0][5] / cnt, mz = sred[0][6] / cnt;
            float n = sqrtf(mx * mx + my * my + mz * mz);
            float nn = fmaxf(n, 1e-12f);
            mx = mx / nn; my = my / nn; mz = mz / nn;
            float n2 = sqrtf(mx * mx + my * my + mz * mz);
            means[4] = mx; means[5] = my; means[6] = mz; means[7] = n2;
        }
    }
}

// ---------------- K3: per-row inlier test, bitmaps rewritten in place -------
__global__ void k_row_inlier(const float* __restrict__ depth,
                             const float* __restrict__ Kinv,
                             const float* __restrict__ means,
                             u64* __restrict__ bitL, u64* __restrict__ bitR,
                             int* __restrict__ cntL, int* __restrict__ cntR) {
#pragma clang fp contract(off)
    int y = blockIdx.x, t = threadIdx.x;
    __shared__ u64 wL[32], wR[32];
    int nz = 0;
    if (t < 32) {
        u64 a = bitL[(size_t)y * 32 + t];
        u64 b = bitR[(size_t)y * 32 + t];
        wL[t] = a; wR[t] = b;
        nz = ((a | b) != 0ull) ? 1 : 0;
    }
    int anyblk = __syncthreads_or(nz);
    if (!anyblk) {
        if (t == 0) { cntL[y] = 0; cntR[y] = 0; }
        return;
    }
    unsigned rbL = (unsigned)((wL[t >> 3] >> ((t & 7) * 8)) & 0xFFull);
    unsigned rbR = (unsigned)((wR[t >> 3] >> ((t & 7) * 8)) & 0xFFull);
    unsigned bAny = rbL | rbR;
    unsigned ibL = 0, ibR = 0;
    if (bAny) {
        K9 kk;
#pragma unroll
        for (int i = 0; i < 9; ++i) kk.k[i] = Kinv[i];
        float m0 = means[0], m1 = means[1], m2 = means[2], m3 = means[3];
        float m4 = means[4], m5 = means[5], m6 = means[6], m7 = means[7];
        for (int j = 0; j < 8; ++j) {
            if (!((bAny >> j) & 1u)) continue;
            int x = t * 8 + j;
            float nx = 0.f, ny = 0.f, nz2 = 0.f;
            if (x > 0 && x < W - 1 && y > 0 && y < H - 1) {
                F3 n = surfNormal(depth, kk, y, x);
                nx = n.x; ny = n.y; nz2 = n.z;
            }
            float nn = sqrtf(nx * nx + ny * ny + nz2 * nz2);
            float dn = fmaxf(nn, 1e-8f);
            if ((rbL >> j) & 1u) {
                float dot = nx * m0 + ny * m1 + nz2 * m2;
                float c = dot / (dn * fmaxf(m3, 1e-8f));
                if (c > THRC) ibL |= (1u << j);
            }
            if ((rbR >> j) & 1u) {
                float dot = nx * m4 + ny * m5 + nz2 * m6;
                float c = dot / (dn * fmaxf(m7, 1e-8f));
                if (c > THRC) ibR |= (1u << j);
            }
        }
    }
    __shared__ unsigned char pbL[256], pbR[256];
    pbL[t] = (unsigned char)ibL;
    pbR[t] = (unsigned char)ibR;
    __syncthreads();
    if (t < 32) {
        bitL[(size_t)y * 32 + t] = reinterpret_cast<u64*>(pbL)[t];
        bitR[(size_t)y * 32 + t] = reinterpret_cast<u64*>(pbR)[t];
    }
    // count reduce
    int cl = __popc(ibL), cr = __popc(ibR);
    __shared__ int sw[4][2];
    int wave = t >> 6, lane = t & 63;
    for (int o = 32; o > 0; o >>= 1) { cl += __shfl_down(cl, o, 64); cr += __shfl_down(cr, o, 64); }
    if (lane == 0) { sw[wave][0] = cl; sw[wave][1] = cr; }
    __syncthreads();
    if (t == 0) {
        cntL[y] = sw[0][0] + sw[1][0] + sw[2][0] + sw[3][0];
        cntR[y] = sw[0][1] + sw[1][1] + sw[2][1] + sw[3][1];
    }
}

// ---------------- K45: fused scan + sample (single block) -------------------
__device__ __forceinline__ int computePos(int i, int N) {
    if (N >= SS) {
        float t = ((float)i * (float)(N - 1)) / 1999.0f;  // float32 reference parity
        return (int)floorf(t);
    } else {
        return min(i, max(N - 1, 0));
    }
}

__global__ void k_scan_sample(const int* __restrict__ cntL, const int* __restrict__ cntR,
                              const u64* __restrict__ bitL, const u64* __restrict__ bitR,
                              int* __restrict__ totals, int* __restrict__ rowAcc) {
    int t = threadIdx.x;  // 1024 threads
    // zero rowAcc (replaces memset)
    for (int i = t; i < 4 * H; i += 1024) rowAcc[i] = 0;

    __shared__ int tsL[1024], tsR[1024];
    __shared__ int cumL[H + 1], cumR[H + 1];
    int r0 = 2 * t, r1 = 2 * t + 1;
    int c0L = (r0 < H) ? cntL[r0] : 0;
    int c0R = (r0 < H) ? cntR[r0] : 0;
    int c1L = (r1 < H) ? cntL[r1] : 0;
    int c1R = (r1 < H) ? cntR[r1] : 0;
    int sl = c0L + c1L, sr = c0R + c1R;
    tsL[t] = sl; tsR[t] = sr;
    __syncthreads();
    for (int off = 1; off < 1024; off <<= 1) {
        int vl = 0, vr = 0;
        if (t >= off) { vl = tsL[t - off]; vr = tsR[t - off]; }
        __syncthreads();
        tsL[t] += vl; tsR[t] += vr;
        __syncthreads();
    }
    int excL = tsL[t] - sl, excR = tsR[t] - sr;
    if (r0 < H) { cumL[r0] = excL;       cumR[r0] = excR; }
    if (r1 < H) { cumL[r1] = excL + c0L; cumR[r1] = excR + c0R; }
    if (t == 1023) {
        cumL[H] = tsL[1023]; cumR[H] = tsR[1023];
        totals[0] = cumL[H]; totals[1] = cumR[H];
        totals[2] = (cumL[H] > 0 && cumR[H] > 0) ? 1 : 0;
        totals[3] = 0;
    }
    __syncthreads();
    int Nl = cumL[H], Nr = cumR[H];
    if (!(Nl > 0 && Nr > 0)) return;  // invalid cluster -> output = depth

    // left samples
    for (int i = t; i < SS; i += 1024) {
        int pos = computePos(i, Nl);
        // upper_bound over cumL[0..H] -> first idx with cum > pos; row = idx-1
        int lo = 0, hi = H + 1;
        while (lo < hi) { int mid = (lo + hi) >> 1; if (cumL[mid] <= pos) lo = mid + 1; else hi = mid; }
        int row = lo - 1;
        int k = pos - cumL[row];
        const u64* wr = bitL + (size_t)row * 32;
        int c = 0, x = 0;
        for (int wj = 0; wj < 32; ++wj) {
            u64 w = wr[wj];
            int pc = __popcll(w);
            if (c + pc > k) {
                int need = k - c;
                while (need--) w &= (w - 1);
                x = wj * 64 + (__ffsll((unsigned long long)w) - 1);
                break;
            }
            c += pc;
        }
        atomicAdd(&rowAcc[row], x);
        atomicAdd(&rowAcc[H + row], 1);
    }
    // right samples
    for (int i = t; i < SS; i += 1024) {
        int pos = computePos(i, Nr);
        int lo = 0, hi = H + 1;
        while (lo < hi) { int mid = (lo + hi) >> 1; if (cumR[mid] <= pos) lo = mid + 1; else hi = mid; }
        int row = lo - 1;
        int k = pos - cumR[row];
        const u64* wr = bitR + (size_t)row * 32;
        int c = 0, x = 0;
        for (int wj = 0; wj < 32; ++wj) {
            u64 w = wr[wj];
            int pc = __popcll(w);
            if (c + pc > k) {
                int need = k - c;
                while (need--) w &= (w - 1);
                x = wj * 64 + (__ffsll((unsigned long long)w) - 1);
                break;
            }
            c += pc;
        }
        atomicAdd(&rowAcc[2 * H + row], x);
        atomicAdd(&rowAcc[3 * H + row], 1);
    }
}

// ---------------- K6: per-row interpolation + output ------------------------
__global__ void k_out(const float* __restrict__ depth, const int* __restrict__ mask,
                      const int* __restrict__ rowAcc, const int* __restrict__ totals,
                      float* __restrict__ out) {
#pragma clang fp contract(off)
    int y = blockIdx.x, t = threadIdx.x;
    __shared__ int sAny;
    __shared__ float sld, srd, slx, srx;
    __shared__ int svalid;
    if (t == 0) sAny = 0;
    __syncthreads();
    int m8[8]; float d8[8];
    int any = 0;
#pragma unroll
    for (int j = 0; j < 8; ++j) {
        int x = j * 256 + t;
        m8[j] = mask[(size_t)y * W + x];
        d8[j] = depth[(size_t)y * W + x];
        any |= m8[j];
    }
    if (any) atomicOr(&sAny, 1);
    __syncthreads();
    if (t == 0) {
        int lc = rowAcc[H + y], rc = rowAcc[3 * H + y];
        float lmean = (float)rowAcc[y] / fmaxf((float)lc, 1.0f);
        float rmean = (float)rowAcc[2 * H + y] / fmaxf((float)rc, 1.0f);
        int lx = min(max((int)rintf(lmean), 0), W - 1);
        int rx = min(max((int)rintf(rmean), 0), W - 1);
        float ld = depth[(size_t)y * W + lx], rd = depth[(size_t)y * W + rx];
        int valid = (lc > 0) && (rc > 0) && (totals[2] != 0) &&
                    (!isnan(ld)) && (!isnan(rd)) && (sAny != 0);
        sld = ld; srd = rd; slx = (float)lx; srx = (float)rx; svalid = valid;
    }
    __syncthreads();
#pragma unroll
    for (int j = 0; j < 8; ++j) {
        int x = j * 256 + t;
        float o = d8[j];
        if (m8[j] && svalid) {
            float r = ((float)x - slx) / ((srx - slx) + 1e-6f);
            r = fminf(fmaxf(r, 0.0f), 1.0f);
            o = (1.0f - r) * sld + r * srd;
        }
        out[(size_t)y * W + x] = o;
    }
}

// ---------------- launcher ---------------------------------------------------
extern "C" void kernel_launch(void* const* d_in, const int* in_sizes, int n_in,
                              void* d_out, int out_size, void* d_ws, size_t ws_size,
                              hipStream_t stream) {
    const float* depth = (const float*)d_in[0];
    const int*   mask  = (const int*)d_in[1];
    const float* Kinv  = (const float*)d_in[2];
    float* out = (float*)d_out;
    char* ws = (char*)d_ws;

    u64* bitL = (u64*)(ws + OFF_BITL);
    u64* bitR = (u64*)(ws + OFF_BITR);
    float* partials = (float*)(ws + OFF_PART);
    float* means    = (float*)(ws + OFF_MEANS);
    int* cntL = (int*)(ws + OFF_CNTL);
    int* cntR = (int*)(ws + OFF_CNTR);
    int* totals = (int*)(ws + OFF_TOT);
    int* rowAcc = (int*)(ws + OFF_ROW);

    k_row_region<<<H, 256, 0, stream>>>(depth, mask, Kinv, bitL, bitR, partials);
    k_mean<<<1, 256, 0, stream>>>(partials, means);
    k_row_inlier<<<H, 256, 0, stream>>>(depth, Kinv, means, bitL, bitR, cntL, cntR);
    k_scan_sample<<<1, 1024, 0, stream>>>(cntL, cntR, bitL, bitR, totals, rowAcc);
    k_out<<<H, 256, 0, stream>>>(depth, mask, rowAcc, totals, out);
}